// Round 1
// baseline (413.193 us; speedup 1.0000x reference)
//
#include <hip/hip_runtime.h>
#include <cstdint>
#include <cstddef>

#define B_DIM 512
#define T_DIM 200
#define D_DIM 512
#define NPAD  208   // N padded to 13*16
#define NKG   28    // K padded to 224 = 28 groups of 8
#define NT    13    // n-tiles of 16
#define KS_STEPS 7  // 224 / 32
// LDS slice per wave: only kg 0..24 stored (t=0..199); kg 25..27 are always
// zero and are handled by an exec-masked A-frag (a=0 for g>=1 at ks==6).
// 25*16*8 = 3200 shorts + 8 pad shorts (16 B) so the 4 wave slices stagger
// LDS banks by 4 (6416 B stride -> w*4 bank offset), cutting the staging
// scatter-write conflict from 16-way to ~4-way.
#define SLICE 3208

typedef short  short8  __attribute__((ext_vector_type(8)));
typedef float  floatx4 __attribute__((ext_vector_type(4)));

__device__ __forceinline__ unsigned short f2bf(float f) {
  unsigned int u = __float_as_uint(f);
  u += 0x7fffu + ((u >> 16) & 1u);   // round-to-nearest-even
  return (unsigned short)(u >> 16);
}
__device__ __forceinline__ float bf2f(unsigned short h) {
  return __uint_as_float(((unsigned int)h) << 16);
}

// W (200x200 fp32) -> bf16, padded 224x208, B-fragment layout [k/8][n][k%8]
__global__ void prep_w_kernel(const float* __restrict__ W,
                              unsigned short* __restrict__ wf) {
  int idx = blockIdx.x * blockDim.x + threadIdx.x;
  if (idx >= NKG * 8 * NPAD) return;
  int k = idx / NPAD;
  int n = idx - k * NPAD;
  float v = (k < T_DIM && n < T_DIM) ? W[k * T_DIM + n] : 0.0f;
  wf[((size_t)(k >> 3) * NPAD + n) * 8 + (k & 7)] = f2bf(v);
}

// Each wave owns a 16-col d-tile of one batch item. Staging is now
// BLOCK-COOPERATIVE and fully coalesced: 256 threads load float4 row-slices
// of the block's 64-col window (each wave instruction = 4 complete 256 B
// contiguous rows), convert to bf16, and scatter into the owning wave's
// frag-layout LDS slice. One __syncthreads, then the K-loop/epilogue are
// wave-autonomous as before.
// launch_bounds(256,6): 24 waves/CU. VGPR demand ~70 (acc 52 + pipe + misc),
// budget at 6 waves/EU is ~80; LDS 4*6416=25,664 B/block -> 6 blocks/CU
// (153,984 <= 163,840).
__global__ __launch_bounds__(256, 6)
void attn_kernel(const float* __restrict__ X,
                 const unsigned short* __restrict__ wf,
                 const float* __restrict__ bias,
                 float* __restrict__ out) {
  __shared__ __align__(16) unsigned short Xa[4 * SLICE];

  const int tid  = threadIdx.x;
  const int wv   = tid >> 6;
  const int lane = tid & 63;
  const int l15  = lane & 15;
  const int g    = lane >> 4;

  const int bid  = blockIdx.x;
  const int bb   = bid >> 3;              // batch item (8 blocks per item)
  const int dblk = (bid & 7) << 6;        // block's 64-col origin
  const int d0   = dblk + (wv << 4);      // this wave's 16-col tile

  // ---- cooperative staging: i = t*16 + c4 covers 200 rows x 16 float4.
  // Lane->addr: consecutive tids cover one 256 B row-slice (16 x float4),
  // a wave instruction covers 4 full rows -> perfectly coalesced.
  {
    const float* xb = X + (size_t)bb * (T_DIM * D_DIM) + dblk;
    #pragma unroll
    for (int it = 0; it < 13; ++it) {
      int i = it * 256 + tid;
      if (i < 3200) {
        int t  = i >> 4;
        int c4 = i & 15;
        float4 v = *(const float4*)(xb + (size_t)t * D_DIM + (c4 << 2));
        // target wave slice = c4>>2; col within wave = (c4&3)*4 + e
        unsigned short* dst = Xa + (c4 >> 2) * SLICE
                            + ((t >> 3) * 16 + ((c4 & 3) << 2)) * 8 + (t & 7);
        dst[0]  = f2bf(v.x);
        dst[8]  = f2bf(v.y);
        dst[16] = f2bf(v.z);
        dst[24] = f2bf(v.w);
      }
    }
  }
  __syncthreads();

  unsigned short* Xw = Xa + wv * SLICE;

  floatx4 acc[NT];
  #pragma unroll
  for (int nt = 0; nt < NT; ++nt)
    acc[nt] = (floatx4){0.f, 0.f, 0.f, 0.f};

  // ---- K-loop: A-frags from own LDS slice, B-frags stream from L2-resident
  // wf. ks==6 reads kg 24 for g==0 only; kg 25..27 (t>=200) are identically
  // zero -> exec-masked a=0 (wf rows there are zero anyway).
  #pragma unroll
  for (int ks = 0; ks < KS_STEPS; ++ks) {
    const int kg = ks * 4 + g;
    short8 a = (short8){0, 0, 0, 0, 0, 0, 0, 0};
    if (ks < 6 || g == 0)
      a = *(const short8*)&Xw[(kg * 16 + l15) * 8];
    const unsigned short* wp = wf + ((size_t)kg * NPAD + l15) * 8;
    #pragma unroll
    for (int nt = 0; nt < NT; ++nt) {
      short8 bfr = *(const short8*)(wp + nt * 16 * 8);
      acc[nt] = __builtin_amdgcn_mfma_f32_16x16x32_bf16(a, bfr, acc[nt], 0, 0, 0);
    }
  }

  // ---- fused epilogue: p = exp(tanh(z)); tanh bounded in [-1,1] => softmax
  // needs no max pass (exp in [0.37,2.72], sum in [73,544]).
  // C/D layout: col = lane&15 (= t within tile), row m = g*4 + r.
  float part[4] = {0.f, 0.f, 0.f, 0.f};
  float rs[4]   = {0.f, 0.f, 0.f, 0.f};
  #pragma unroll
  for (int nt = 0; nt < NT; ++nt) {
    const int t = nt * 16 + l15;
    const bool valid = (t < T_DIM);
    const float bvn = valid ? bias[t] : 0.0f;   // bias indexed by n == t here
    const unsigned short* xp = &Xw[((t >> 3) * 16) * 8 + (t & 7)];
    #pragma unroll
    for (int r = 0; r < 4; ++r) {
      if (valid) {
        float z  = acc[nt][r] + bvn;
        float e  = __expf(2.0f * z);              // tanh = 1 - 2/(e^{2z}+1)
        float th = 1.0f - __fdividef(2.0f, e + 1.0f);
        float p  = __expf(th);
        rs[r]   += p;
        const int m = g * 4 + r;
        part[r] += p * bf2f(xp[m * 8]);           // X[t][d0+m]
      }
    }
  }
  // reduce over the 16 t-lanes (each (g,r) is a distinct output row)
  #pragma unroll
  for (int off = 1; off <= 8; off <<= 1)
    #pragma unroll
    for (int r = 0; r < 4; ++r) {
      part[r] += __shfl_xor(part[r], off, 16);
      rs[r]   += __shfl_xor(rs[r],   off, 16);
    }

  if (l15 == 0) {
    #pragma unroll
    for (int r = 0; r < 4; ++r)
      out[(size_t)bb * D_DIM + d0 + g * 4 + r] = part[r] * __frcp_rn(rs[r]);
  }
}

extern "C" void kernel_launch(void* const* d_in, const int* in_sizes, int n_in,
                              void* d_out, int out_size, void* d_ws, size_t ws_size,
                              hipStream_t stream) {
  const float* X  = (const float*)d_in[0];
  const float* W  = (const float*)d_in[1];
  const float* bs = (const float*)d_in[2];
  float* out = (float*)d_out;
  unsigned short* wf = (unsigned short*)d_ws;  // needs 224*208*2 = 93,184 B

  const int wtot = NKG * 8 * NPAD;
  hipLaunchKernelGGL(prep_w_kernel, dim3((wtot + 255) / 256), dim3(256), 0, stream,
                     W, wf);
  // 16384 waves = 512 b * 32 d-tiles; 4 cooperative waves per block
  hipLaunchKernelGGL(attn_kernel, dim3(4096), dim3(256), 0, stream,
                     X, wf, bs, out);
}

// Round 2
// 337.551 us; speedup vs baseline: 1.2241x; 1.2241x over previous
//
#include <hip/hip_runtime.h>
#include <cstdint>
#include <cstddef>

#define B_DIM 512
#define T_DIM 200
#define D_DIM 512
#define NPAD  208   // N padded to 13*16
#define NKG   28    // K padded to 224 = 28 groups of 8
#define NT    13    // n-tiles of 16
#define KS_STEPS 7  // 224 / 32
// LDS slice per wave: only kg 0..24 stored (t=0..199); kg 25..27 are always
// zero and are handled by an exec-masked A-frag (a=0 for g>=1 at ks==6).
// 25*16*8 = 3200 shorts + 8 pad shorts (16 B) so the 4 wave slices stagger
// LDS banks by 4 (6416 B stride -> w*4 bank offset), cutting the staging
// scatter-write conflict from 16-way to ~4-way.
// Block LDS = 25,664 B (rounds to 26,112) -> 6 blocks/CU (LDS-limited).
#define SLICE 3208

typedef short  short8  __attribute__((ext_vector_type(8)));
typedef float  floatx4 __attribute__((ext_vector_type(4)));

__device__ __forceinline__ unsigned short f2bf(float f) {
  unsigned int u = __float_as_uint(f);
  u += 0x7fffu + ((u >> 16) & 1u);   // round-to-nearest-even
  return (unsigned short)(u >> 16);
}
__device__ __forceinline__ float bf2f(unsigned short h) {
  return __uint_as_float(((unsigned int)h) << 16);
}

// W (200x200 fp32) -> bf16, padded 224x208, B-fragment layout [k/8][n][k%8]
__global__ void prep_w_kernel(const float* __restrict__ W,
                              unsigned short* __restrict__ wf) {
  int idx = blockIdx.x * blockDim.x + threadIdx.x;
  if (idx >= NKG * 8 * NPAD) return;
  int k = idx / NPAD;
  int n = idx - k * NPAD;
  float v = (k < T_DIM && n < T_DIM) ? W[k * T_DIM + n] : 0.0f;
  wf[((size_t)(k >> 3) * NPAD + n) * 8 + (k & 7)] = f2bf(v);
}

// Each wave owns a 16-col d-tile of one batch item. Staging is
// BLOCK-COOPERATIVE and fully coalesced: 256 threads load float4 row-slices
// of the block's 64-col window (each wave instruction = 4 complete 256 B
// contiguous rows), convert to bf16, and scatter into the owning wave's
// frag-layout LDS slice. One __syncthreads, then the K-loop/epilogue are
// wave-autonomous.
// launch_bounds(256,4): 128-reg budget -> NO SPILLS. R1 showed (256,6)
// forces <=64 regs (wave slots step at VGPR=64), spilling acc[13] ->
// 189 MB scratch writes, 234 us. Actual VGPR use ~64 permits 8 waves/EU,
// so occupancy is LDS-limited at 6 blocks/CU = 75% without any forcing.
__global__ __launch_bounds__(256, 4)
void attn_kernel(const float* __restrict__ X,
                 const unsigned short* __restrict__ wf,
                 const float* __restrict__ bias,
                 float* __restrict__ out) {
  __shared__ __align__(16) unsigned short Xa[4 * SLICE];

  const int tid  = threadIdx.x;
  const int wv   = tid >> 6;
  const int lane = tid & 63;
  const int l15  = lane & 15;
  const int g    = lane >> 4;

  const int bid  = blockIdx.x;
  const int bb   = bid >> 3;              // batch item (8 blocks per item)
  const int dblk = (bid & 7) << 6;        // block's 64-col origin
  const int d0   = dblk + (wv << 4);      // this wave's 16-col tile

  // ---- cooperative staging: i = t*16 + c4 covers 200 rows x 16 float4.
  // Lane->addr: consecutive tids cover one 256 B row-slice (16 x float4),
  // a wave instruction covers 4 full rows -> perfectly coalesced.
  {
    const float* xb = X + (size_t)bb * (T_DIM * D_DIM) + dblk;
    #pragma unroll
    for (int it = 0; it < 13; ++it) {
      int i = it * 256 + tid;
      if (i < 3200) {
        int t  = i >> 4;
        int c4 = i & 15;
        float4 v = *(const float4*)(xb + (size_t)t * D_DIM + (c4 << 2));
        // target wave slice = c4>>2; col within wave = (c4&3)*4 + e
        unsigned short* dst = Xa + (c4 >> 2) * SLICE
                            + ((t >> 3) * 16 + ((c4 & 3) << 2)) * 8 + (t & 7);
        dst[0]  = f2bf(v.x);
        dst[8]  = f2bf(v.y);
        dst[16] = f2bf(v.z);
        dst[24] = f2bf(v.w);
      }
    }
  }
  __syncthreads();

  unsigned short* Xw = Xa + wv * SLICE;

  floatx4 acc[NT];
  #pragma unroll
  for (int nt = 0; nt < NT; ++nt)
    acc[nt] = (floatx4){0.f, 0.f, 0.f, 0.f};

  // ---- K-loop: A-frags from own LDS slice, B-frags stream from L2-resident
  // wf. ks==6 reads kg 24 for g==0 only; kg 25..27 (t>=200) are identically
  // zero -> exec-masked a=0 (wf rows there are zero anyway).
  #pragma unroll
  for (int ks = 0; ks < KS_STEPS; ++ks) {
    const int kg = ks * 4 + g;
    short8 a = (short8){0, 0, 0, 0, 0, 0, 0, 0};
    if (ks < 6 || g == 0)
      a = *(const short8*)&Xw[(kg * 16 + l15) * 8];
    const unsigned short* wp = wf + ((size_t)kg * NPAD + l15) * 8;
    #pragma unroll
    for (int nt = 0; nt < NT; ++nt) {
      short8 bfr = *(const short8*)(wp + nt * 16 * 8);
      acc[nt] = __builtin_amdgcn_mfma_f32_16x16x32_bf16(a, bfr, acc[nt], 0, 0, 0);
    }
  }

  // ---- fused epilogue: p = exp(tanh(z)); tanh bounded in [-1,1] => softmax
  // needs no max pass (exp in [0.37,2.72], sum in [73,544]).
  // C/D layout: col = lane&15 (= t within tile), row m = g*4 + r.
  float part[4] = {0.f, 0.f, 0.f, 0.f};
  float rs[4]   = {0.f, 0.f, 0.f, 0.f};
  #pragma unroll
  for (int nt = 0; nt < NT; ++nt) {
    const int t = nt * 16 + l15;
    const bool valid = (t < T_DIM);
    const float bvn = valid ? bias[t] : 0.0f;   // bias indexed by n == t here
    const unsigned short* xp = &Xw[((t >> 3) * 16) * 8 + (t & 7)];
    #pragma unroll
    for (int r = 0; r < 4; ++r) {
      if (valid) {
        float z  = acc[nt][r] + bvn;
        float e  = __expf(2.0f * z);              // tanh = 1 - 2/(e^{2z}+1)
        float th = 1.0f - __fdividef(2.0f, e + 1.0f);
        float p  = __expf(th);
        rs[r]   += p;
        const int m = g * 4 + r;
        part[r] += p * bf2f(xp[m * 8]);           // X[t][d0+m]
      }
    }
  }
  // reduce over the 16 t-lanes (each (g,r) is a distinct output row)
  #pragma unroll
  for (int off = 1; off <= 8; off <<= 1)
    #pragma unroll
    for (int r = 0; r < 4; ++r) {
      part[r] += __shfl_xor(part[r], off, 16);
      rs[r]   += __shfl_xor(rs[r],   off, 16);
    }

  if (l15 == 0) {
    #pragma unroll
    for (int r = 0; r < 4; ++r)
      out[(size_t)bb * D_DIM + d0 + g * 4 + r] = part[r] * __frcp_rn(rs[r]);
  }
}

extern "C" void kernel_launch(void* const* d_in, const int* in_sizes, int n_in,
                              void* d_out, int out_size, void* d_ws, size_t ws_size,
                              hipStream_t stream) {
  const float* X  = (const float*)d_in[0];
  const float* W  = (const float*)d_in[1];
  const float* bs = (const float*)d_in[2];
  float* out = (float*)d_out;
  unsigned short* wf = (unsigned short*)d_ws;  // needs 224*208*2 = 93,184 B

  const int wtot = NKG * 8 * NPAD;
  hipLaunchKernelGGL(prep_w_kernel, dim3((wtot + 255) / 256), dim3(256), 0, stream,
                     W, wf);
  // 16384 waves = 512 b * 32 d-tiles; 4 cooperative waves per block
  hipLaunchKernelGGL(attn_kernel, dim3(4096), dim3(256), 0, stream,
                     X, wf, bs, out);
}

// Round 3
// 326.836 us; speedup vs baseline: 1.2642x; 1.0328x over previous
//
#include <hip/hip_runtime.h>
#include <cstdint>
#include <cstddef>

#define B_DIM 512
#define T_DIM 200
#define D_DIM 512
#define NPAD  208   // N padded to 13*16
#define NKG   28    // K padded to 224 = 28 groups of 8
#define NT    13    // n-tiles of 16
#define KS_STEPS 7  // 224 / 32
// LDS slice per wave: only kg 0..24 stored (t=0..199); kg 25..27 are always
// zero and are handled by an exec-masked A-frag (a=0 for g>=1 at ks==6).
// 25*16*8 = 3200 shorts + 8 pad shorts (16 B) -> 4 wave slices stagger banks.
// Block LDS = 25,664 B (rounds to 26,112).
#define SLICE 3208

typedef short  short8  __attribute__((ext_vector_type(8)));
typedef float  floatx4 __attribute__((ext_vector_type(4)));

__device__ __forceinline__ unsigned short f2bf(float f) {
  unsigned int u = __float_as_uint(f);
  u += 0x7fffu + ((u >> 16) & 1u);   // round-to-nearest-even
  return (unsigned short)(u >> 16);
}
__device__ __forceinline__ float bf2f(unsigned short h) {
  return __uint_as_float(((unsigned int)h) << 16);
}

// W (200x200 fp32) -> bf16, padded 224x208, B-fragment layout [k/8][n][k%8]
__global__ void prep_w_kernel(const float* __restrict__ W,
                              unsigned short* __restrict__ wf) {
  int idx = blockIdx.x * blockDim.x + threadIdx.x;
  if (idx >= NKG * 8 * NPAD) return;
  int k = idx / NPAD;
  int n = idx - k * NPAD;
  float v = (k < T_DIM && n < T_DIM) ? W[k * T_DIM + n] : 0.0f;
  wf[((size_t)(k >> 3) * NPAD + n) * 8 + (k & 7)] = f2bf(v);
}

// R2 post-mortem: VGPR_Count=64 with acc=52 regs -> only ONE wf B-frag load
// in flight; K-loop serialized at L1/L2 latency (~91 x 150 cyc exposed).
// Fix: explicit register double-buffer of B-frags sized to the 128-reg
// budget: b0[7] + b1[6] (52 regs) + acc (52) + a_cur/a_nxt (8) ~= 120.
// While half-A MFMAs run, half-B loads are in flight, and vice versa.
// launch_bounds(256,4): 128-reg budget, no spills (R1: forcing 6 waves/EU
// spilled acc -> 189 MB scratch, 234 us).
__global__ __launch_bounds__(256, 4)
void attn_kernel(const float* __restrict__ X,
                 const unsigned short* __restrict__ wf,
                 const float* __restrict__ bias,
                 float* __restrict__ out) {
  __shared__ __align__(16) unsigned short Xa[4 * SLICE];

  const int tid  = threadIdx.x;
  const int wv   = tid >> 6;
  const int lane = tid & 63;
  const int l15  = lane & 15;
  const int g    = lane >> 4;

  const int bid  = blockIdx.x;
  const int bb   = bid >> 3;              // batch item (8 blocks per item)
  const int dblk = (bid & 7) << 6;        // block's 64-col origin
  const int d0   = dblk + (wv << 4);      // this wave's 16-col tile

  // ---- cooperative staging: i = t*16 + c4 covers 200 rows x 16 float4.
  // Consecutive tids cover one 256 B row-slice -> perfectly coalesced.
  {
    const float* xb = X + (size_t)bb * (T_DIM * D_DIM) + dblk;
    #pragma unroll
    for (int it = 0; it < 13; ++it) {
      int i = it * 256 + tid;
      if (i < 3200) {
        int t  = i >> 4;
        int c4 = i & 15;
        float4 v = *(const float4*)(xb + (size_t)t * D_DIM + (c4 << 2));
        unsigned short* dst = Xa + (c4 >> 2) * SLICE
                            + ((t >> 3) * 16 + ((c4 & 3) << 2)) * 8 + (t & 7);
        dst[0]  = f2bf(v.x);
        dst[8]  = f2bf(v.y);
        dst[16] = f2bf(v.z);
        dst[24] = f2bf(v.w);
      }
    }
  }
  __syncthreads();

  unsigned short* Xw = Xa + wv * SLICE;

  floatx4 acc[NT];
  #pragma unroll
  for (int nt = 0; nt < NT; ++nt)
    acc[nt] = (floatx4){0.f, 0.f, 0.f, 0.f};

#define BLOAD(dst, kg, nt) \
  (dst) = *(const short8*)(wf + ((size_t)(kg) * NPAD + (nt) * 16 + l15) * 8)

  // ---- K-loop, software-pipelined at half-ks granularity.
  short8 b0[7], b1[6];
  short8 a_cur, a_nxt;

  // prologue: ks=0 A-frag + first half B-frags
  a_cur = *(const short8*)&Xw[((g * 16) + l15) * 8];
  #pragma unroll
  for (int nt = 0; nt < 7; ++nt) BLOAD(b0[nt], g, nt);

  #pragma unroll
  for (int ks = 0; ks < KS_STEPS; ++ks) {
    const int kg = ks * 4 + g;
    // issue second-half loads for this ks (in flight during b0 MFMAs)
    #pragma unroll
    for (int j = 0; j < 6; ++j) BLOAD(b1[j], kg, 7 + j);
    #pragma unroll
    for (int nt = 0; nt < 7; ++nt)
      acc[nt] = __builtin_amdgcn_mfma_f32_16x16x32_bf16(a_cur, b0[nt], acc[nt], 0, 0, 0);
    // prefetch next ks's first half + A-frag (in flight during b1 MFMAs)
    if (ks < 6) {
      const int kgn = kg + 4;
      #pragma unroll
      for (int nt = 0; nt < 7; ++nt) BLOAD(b0[nt], kgn, nt);
      // kg 25..27 (t>=200) are identically zero -> exec-masked a=0; only
      // g==0 reads kg 24 at ks==6. (Stored LDS slice covers kg 0..24.)
      if (ks < 5 || g == 0)
        a_nxt = *(const short8*)&Xw[((kgn * 16) + l15) * 8];
      else
        a_nxt = (short8){0, 0, 0, 0, 0, 0, 0, 0};
    }
    #pragma unroll
    for (int j = 0; j < 6; ++j)
      acc[7 + j] = __builtin_amdgcn_mfma_f32_16x16x32_bf16(a_cur, b1[j], acc[7 + j], 0, 0, 0);
    a_cur = a_nxt;
  }
#undef BLOAD

  // ---- fused epilogue: p = exp(tanh(z)); tanh bounded in [-1,1] => softmax
  // needs no max pass (exp in [0.37,2.72], sum in [73,544]).
  // C/D layout: col = lane&15 (= t within tile), row m = g*4 + r.
  float part[4] = {0.f, 0.f, 0.f, 0.f};
  float rs[4]   = {0.f, 0.f, 0.f, 0.f};
  #pragma unroll
  for (int nt = 0; nt < NT; ++nt) {
    const int t = nt * 16 + l15;
    const bool valid = (t < T_DIM);
    const float bvn = valid ? bias[t] : 0.0f;   // bias indexed by n == t here
    const unsigned short* xp = &Xw[((t >> 3) * 16) * 8 + (t & 7)];
    #pragma unroll
    for (int r = 0; r < 4; ++r) {
      if (valid) {
        float z  = acc[nt][r] + bvn;
        float e  = __expf(2.0f * z);              // tanh = 1 - 2/(e^{2z}+1)
        float th = 1.0f - __fdividef(2.0f, e + 1.0f);
        float p  = __expf(th);
        rs[r]   += p;
        const int m = g * 4 + r;
        part[r] += p * bf2f(xp[m * 8]);           // X[t][d0+m]
      }
    }
  }
  // reduce over the 16 t-lanes (each (g,r) is a distinct output row)
  #pragma unroll
  for (int off = 1; off <= 8; off <<= 1)
    #pragma unroll
    for (int r = 0; r < 4; ++r) {
      part[r] += __shfl_xor(part[r], off, 16);
      rs[r]   += __shfl_xor(rs[r],   off, 16);
    }

  if (l15 == 0) {
    #pragma unroll
    for (int r = 0; r < 4; ++r)
      out[(size_t)bb * D_DIM + d0 + g * 4 + r] = part[r] * __frcp_rn(rs[r]);
  }
}

extern "C" void kernel_launch(void* const* d_in, const int* in_sizes, int n_in,
                              void* d_out, int out_size, void* d_ws, size_t ws_size,
                              hipStream_t stream) {
  const float* X  = (const float*)d_in[0];
  const float* W  = (const float*)d_in[1];
  const float* bs = (const float*)d_in[2];
  float* out = (float*)d_out;
  unsigned short* wf = (unsigned short*)d_ws;  // needs 224*208*2 = 93,184 B

  const int wtot = NKG * 8 * NPAD;
  hipLaunchKernelGGL(prep_w_kernel, dim3((wtot + 255) / 256), dim3(256), 0, stream,
                     W, wf);
  // 16384 waves = 512 b * 32 d-tiles; 4 cooperative waves per block
  hipLaunchKernelGGL(attn_kernel, dim3(4096), dim3(256), 0, stream,
                     X, wf, bs, out);
}